// Round 1
// baseline (3545.169 us; speedup 1.0000x reference)
//
#include <hip/hip_runtime.h>
#include <stdint.h>

#define B 64
#define U 512
#define EDIM 512
#define V 32000
#define T_STEPS 20
#define ZW 2048   // 4*U

// ---------------- ws layout ----------------
// slots  : u64 [T_STEPS][B]      @ 0        (10240 B, rounded to 16384)
// zpart  : f32 [8][B][ZW]        @ 16384    (4 MiB)
// h      : f32 [B][U]            after zpart
// c      : f32 [B][U]            after h
#define WS_ZPART_OFF 16384
#define WS_ZPART_BYTES (8 * B * ZW * 4)

__device__ __forceinline__ float sigf(float x) { return 1.0f / (1.0f + expf(-x)); }

__global__ __launch_bounds__(256) void reset_slots_kernel(unsigned long long* __restrict__ slots) {
    int gid = blockIdx.x * 256 + threadIdx.x;   // grid covers T_STEPS*B = 1280
    if (gid < T_STEPS * B) slots[gid] = 0ull;
}

// z-partials: grid (32 ug-blocks, 8 k-chunks), block 256.
// Block computes zpart[chunk][b][ug0..ug0+63] for all 64 b over 128 K-elems.
// Thread = (lane=ug offset, bg=b-group of 16), 16 accumulators.
__global__ __launch_bounds__(256) void lstmA_kernel(
    const float* __restrict__ emb, const float* __restrict__ Wx,
    const float* __restrict__ Wh, const float* __restrict__ hprev,
    const unsigned long long* __restrict__ slot_prev,
    float* __restrict__ zpart, int is_first)
{
    __shared__ float xh[128][68];   // [k_local][b], pad 68: 16B-aligned float4, conflicts only on staging writes
    __shared__ int sidx[B];

    const int tid = threadIdx.x;
    const int ublock = blockIdx.x;      // 0..31
    const int chunk = blockIdx.y;       // 0..7 ; k = chunk*128 .. +127  (k<512: x-part, else h-part)
    const int e0 = chunk * 128;

    if (tid < B) {
        int idx = 1;  // GO token
        if (!is_first) {
            unsigned long long k = slot_prev[tid];
            idx = (int)(0xFFFFFFFFu - (unsigned)(k & 0xFFFFFFFFull));
        }
        sidx[tid] = idx;
    }
    __syncthreads();

    // stage 128 x 64 source tile, transposed into LDS
    for (int i = 0; i < 32; ++i) {
        int li = tid + 256 * i;       // 0..8191
        int el = li & 127;
        int b  = li >> 7;
        float v;
        if (chunk < 4) v = emb[(size_t)sidx[b] * EDIM + (e0 + el)];
        else           v = hprev[b * U + (e0 - EDIM + el)];
        xh[el][b] = v;
    }
    __syncthreads();

    const int lane = tid & 63;
    const int bg = tid >> 6;            // 0..3 (wave-uniform)
    const int ug = ublock * 64 + lane;  // 0..2047

    const float* wbase = (chunk < 4) ? (Wx + (size_t)e0 * ZW)
                                     : (Wh + (size_t)(e0 - EDIM) * ZW);
    float acc[16];
#pragma unroll
    for (int j = 0; j < 16; ++j) acc[j] = 0.0f;

#pragma unroll 4
    for (int el = 0; el < 128; ++el) {
        float w = wbase[(size_t)el * ZW + ug];
        const float4* hp = (const float4*)&xh[el][bg * 16];
        float4 a0 = hp[0], a1 = hp[1], a2 = hp[2], a3 = hp[3];
        acc[0]  = fmaf(a0.x, w, acc[0]);  acc[1]  = fmaf(a0.y, w, acc[1]);
        acc[2]  = fmaf(a0.z, w, acc[2]);  acc[3]  = fmaf(a0.w, w, acc[3]);
        acc[4]  = fmaf(a1.x, w, acc[4]);  acc[5]  = fmaf(a1.y, w, acc[5]);
        acc[6]  = fmaf(a1.z, w, acc[6]);  acc[7]  = fmaf(a1.w, w, acc[7]);
        acc[8]  = fmaf(a2.x, w, acc[8]);  acc[9]  = fmaf(a2.y, w, acc[9]);
        acc[10] = fmaf(a2.z, w, acc[10]); acc[11] = fmaf(a2.w, w, acc[11]);
        acc[12] = fmaf(a3.x, w, acc[12]); acc[13] = fmaf(a3.y, w, acc[13]);
        acc[14] = fmaf(a3.z, w, acc[14]); acc[15] = fmaf(a3.w, w, acc[15]);
    }

    float* zp = zpart + (size_t)chunk * (B * ZW) + ug;
#pragma unroll
    for (int j = 0; j < 16; ++j)
        zp[(size_t)(bg * 16 + j) * ZW] = acc[j];
}

// gates + state update: 32768 threads (one per (b,u))
__global__ __launch_bounds__(256) void lstmB_kernel(
    const float* __restrict__ zpart, const float* __restrict__ b_lstm,
    const float* __restrict__ cin, float* __restrict__ hout, float* __restrict__ cout)
{
    int gid = blockIdx.x * 256 + threadIdx.x;  // 0..32767
    int u = gid & (U - 1);
    int b = gid >> 9;
    float z[4];
#pragma unroll
    for (int g = 0; g < 4; ++g) {
        float s = b_lstm[g * U + u];
#pragma unroll
        for (int c = 0; c < 8; ++c)
            s += zpart[(size_t)(c * B + b) * ZW + g * U + u];
        z[g] = s;
    }
    float co = cin[b * U + u];
    float ig = sigf(z[0]);
    float fg = sigf(z[1]);
    float gg = tanhf(z[2]);
    float og = sigf(z[3]);
    float cn = fg * co + ig * gg;
    float hn = og * tanhf(cn);
    cout[b * U + u] = cn;
    hout[b * U + u] = hn;
}

// logits + fused argmax: 500 blocks x 256. Block = 64 v (all 64 b).
// Thread = (lane=v offset, bg=b-group of 16), 16 accumulators.
__global__ __launch_bounds__(256) void logits_kernel(
    const float* __restrict__ h, const float* __restrict__ Wd,
    const float* __restrict__ bd, float* __restrict__ out,
    unsigned long long* __restrict__ slot, int t)
{
    __shared__ float hT[64][68];
    const int tid = threadIdx.x;
    const int lane = tid & 63;
    const int bg = tid >> 6;            // wave-uniform
    const int v = blockIdx.x * 64 + lane;

    float bias = bd[v];
    float acc[16];
#pragma unroll
    for (int j = 0; j < 16; ++j) acc[j] = bias;

    for (int ec = 0; ec < 8; ++ec) {
        __syncthreads();
#pragma unroll
        for (int i = 0; i < 16; ++i) {
            int li = tid + 256 * i;      // 0..4095
            int el = li & 63;
            int b  = li >> 6;
            hT[el][b] = h[b * U + ec * 64 + el];
        }
        __syncthreads();
#pragma unroll 4
        for (int el = 0; el < 64; ++el) {
            float w = Wd[(size_t)(ec * 64 + el) * V + v];
            const float4* hp = (const float4*)&hT[el][bg * 16];
            float4 a0 = hp[0], a1 = hp[1], a2 = hp[2], a3 = hp[3];
            acc[0]  = fmaf(a0.x, w, acc[0]);  acc[1]  = fmaf(a0.y, w, acc[1]);
            acc[2]  = fmaf(a0.z, w, acc[2]);  acc[3]  = fmaf(a0.w, w, acc[3]);
            acc[4]  = fmaf(a1.x, w, acc[4]);  acc[5]  = fmaf(a1.y, w, acc[5]);
            acc[6]  = fmaf(a1.z, w, acc[6]);  acc[7]  = fmaf(a1.w, w, acc[7]);
            acc[8]  = fmaf(a2.x, w, acc[8]);  acc[9]  = fmaf(a2.y, w, acc[9]);
            acc[10] = fmaf(a2.z, w, acc[10]); acc[11] = fmaf(a2.w, w, acc[11]);
            acc[12] = fmaf(a3.x, w, acc[12]); acc[13] = fmaf(a3.y, w, acc[13]);
            acc[14] = fmaf(a3.z, w, acc[14]); acc[15] = fmaf(a3.w, w, acc[15]);
        }
    }

    // write logits: out[b][t][v]
#pragma unroll
    for (int j = 0; j < 16; ++j) {
        int b = bg * 16 + j;
        out[(size_t)b * (T_STEPS * V) + (size_t)t * V + v] = acc[j];
    }

    // fused argmax: monotone-float key, tie-break to smallest v (np.argmax = first max)
#pragma unroll
    for (int j = 0; j < 16; ++j) {
        unsigned ub = __float_as_uint(acc[j]);
        unsigned key32 = (ub & 0x80000000u) ? ~ub : (ub | 0x80000000u);
        unsigned long long key =
            ((unsigned long long)key32 << 32) | (unsigned long long)(0xFFFFFFFFu - (unsigned)v);
#pragma unroll
        for (int d = 32; d > 0; d >>= 1) {
            unsigned long long o = __shfl_down(key, (unsigned)d, 64);
            if (o > key) key = o;
        }
        if (lane == 0) atomicMax(slot + (bg * 16 + j), key);
    }
}

extern "C" void kernel_launch(void* const* d_in, const int* in_sizes, int n_in,
                              void* d_out, int out_size, void* d_ws, size_t ws_size,
                              hipStream_t stream)
{
    const float* h0     = (const float*)d_in[0];
    const float* c0     = (const float*)d_in[1];
    const float* emb    = (const float*)d_in[2];
    const float* Wx     = (const float*)d_in[3];
    const float* Wh     = (const float*)d_in[4];
    const float* b_lstm = (const float*)d_in[5];
    const float* Wd     = (const float*)d_in[6];
    const float* bd     = (const float*)d_in[7];
    float* out = (float*)d_out;

    char* ws = (char*)d_ws;
    unsigned long long* slots = (unsigned long long*)ws;          // [T][B]
    float* zpart = (float*)(ws + WS_ZPART_OFF);                   // [8][B][ZW]
    float* hbuf  = (float*)(ws + WS_ZPART_OFF + WS_ZPART_BYTES);  // [B][U]
    float* cbuf  = hbuf + B * U;                                  // [B][U]

    reset_slots_kernel<<<dim3(5), dim3(256), 0, stream>>>(slots);

    for (int t = 0; t < T_STEPS; ++t) {
        const float* hprev = (t == 0) ? h0 : hbuf;
        const float* cprev = (t == 0) ? c0 : cbuf;
        const unsigned long long* sp = (t == 0) ? slots : (slots + (size_t)(t - 1) * B);

        lstmA_kernel<<<dim3(32, 8), dim3(256), 0, stream>>>(
            emb, Wx, Wh, hprev, sp, zpart, (t == 0) ? 1 : 0);
        lstmB_kernel<<<dim3(128), dim3(256), 0, stream>>>(
            zpart, b_lstm, cprev, hbuf, cbuf);
        logits_kernel<<<dim3(500), dim3(256), 0, stream>>>(
            hbuf, Wd, bd, out, slots + (size_t)t * B, t);
    }
}

// Round 2
// 1723.355 us; speedup vs baseline: 2.0571x; 2.0571x over previous
//
#include <hip/hip_runtime.h>
#include <stdint.h>

#define B 64
#define U 512
#define EDIM 512
#define V 32000
#define T_STEPS 20
#define ZW 2048   // 4*U

// ---------------- ws layout ----------------
// slots  : u64 [T_STEPS][B]      @ 0        (10240 B, rounded to 16384)
// zpart  : f32 [8][B][ZW]        @ 16384    (4 MiB)
// h      : f32 [B][U]            after zpart
// c      : f32 [B][U]            after h
#define WS_ZPART_OFF 16384
#define WS_ZPART_BYTES (8 * B * ZW * 4)

__device__ __forceinline__ float sigf(float x) { return 1.0f / (1.0f + expf(-x)); }

__global__ __launch_bounds__(256) void reset_slots_kernel(unsigned long long* __restrict__ slots) {
    int gid = blockIdx.x * 256 + threadIdx.x;   // grid covers T_STEPS*B = 1280
    if (gid < T_STEPS * B) slots[gid] = 0ull;
}

// z-partials. grid (8 ugtiles, 4 btiles, 8 kchunks), block 256.
// Block: 256 ug x 16 b over a 128-deep K chunk.
// Thread: 4 consecutive ug (lane*4) x 4 consecutive b (tb*4). Per el:
//   1 global dwordx4 of W (coalesced 1KB/wave) + 1 broadcast ds_read_b128 of x/h.
__global__ __launch_bounds__(256) void lstmA_kernel(
    const float* __restrict__ emb, const float* __restrict__ Wx,
    const float* __restrict__ Wh, const float* __restrict__ hprev,
    const unsigned long long* __restrict__ slot_prev,
    float* __restrict__ zpart, int is_first)
{
    __shared__ float xh[128][20];   // [k_local][b], pad 20: rows 80B (16B-aligned), broadcast reads conflict-free
    __shared__ int sidx[16];

    const int tid = threadIdx.x;
    const int ugtile = blockIdx.x;      // 0..7
    const int btile = blockIdx.y;       // 0..3
    const int chunk = blockIdx.z;       // 0..7 ; k<512: x-part, else h-part
    const int e0 = chunk * 128;
    const int b0 = btile * 16;

    if (tid < 16) {
        int idx = 1;  // GO token
        if (!is_first) {
            unsigned long long k = slot_prev[b0 + tid];
            idx = (int)(0xFFFFFFFFu - (unsigned)(k & 0xFFFFFFFFull));
        }
        sidx[tid] = idx;
    }
    __syncthreads();

    // stage 128 el x 16 b tile (transposed) into LDS
#pragma unroll
    for (int i = 0; i < 8; ++i) {
        int li = tid + 256 * i;       // 0..2047
        int el = li & 127;
        int b  = li >> 7;
        float v;
        if (chunk < 4) v = emb[(size_t)sidx[b] * EDIM + (e0 + el)];
        else           v = hprev[(b0 + b) * U + (e0 - EDIM + el)];
        xh[el][b] = v;
    }
    __syncthreads();

    const int lane = tid & 63;
    const int tb = tid >> 6;            // 0..3 (wave-uniform)
    const int ug0 = ugtile * 256 + lane * 4;

    const float* wbase = (chunk < 4) ? (Wx + (size_t)e0 * ZW)
                                     : (Wh + (size_t)(e0 - EDIM) * ZW);
    float acc[4][4];
#pragma unroll
    for (int j = 0; j < 4; ++j)
#pragma unroll
        for (int k = 0; k < 4; ++k) acc[j][k] = 0.0f;

#pragma unroll 8
    for (int el = 0; el < 128; ++el) {
        float4 w = *(const float4*)&wbase[(size_t)el * ZW + ug0];
        float4 hh = *(const float4*)&xh[el][tb * 4];   // broadcast: all lanes same addr
        acc[0][0] = fmaf(hh.x, w.x, acc[0][0]); acc[0][1] = fmaf(hh.x, w.y, acc[0][1]);
        acc[0][2] = fmaf(hh.x, w.z, acc[0][2]); acc[0][3] = fmaf(hh.x, w.w, acc[0][3]);
        acc[1][0] = fmaf(hh.y, w.x, acc[1][0]); acc[1][1] = fmaf(hh.y, w.y, acc[1][1]);
        acc[1][2] = fmaf(hh.y, w.z, acc[1][2]); acc[1][3] = fmaf(hh.y, w.w, acc[1][3]);
        acc[2][0] = fmaf(hh.z, w.x, acc[2][0]); acc[2][1] = fmaf(hh.z, w.y, acc[2][1]);
        acc[2][2] = fmaf(hh.z, w.z, acc[2][2]); acc[2][3] = fmaf(hh.z, w.w, acc[2][3]);
        acc[3][0] = fmaf(hh.w, w.x, acc[3][0]); acc[3][1] = fmaf(hh.w, w.y, acc[3][1]);
        acc[3][2] = fmaf(hh.w, w.z, acc[3][2]); acc[3][3] = fmaf(hh.w, w.w, acc[3][3]);
    }

#pragma unroll
    for (int j = 0; j < 4; ++j) {
        int b = b0 + tb * 4 + j;
        float4 r = make_float4(acc[j][0], acc[j][1], acc[j][2], acc[j][3]);
        *(float4*)&zpart[(size_t)chunk * (B * ZW) + (size_t)b * ZW + ug0] = r;
    }
}

// gates + state update: 32768 threads (one per (b,u))
__global__ __launch_bounds__(256) void lstmB_kernel(
    const float* __restrict__ zpart, const float* __restrict__ b_lstm,
    const float* __restrict__ cin, float* __restrict__ hout, float* __restrict__ cout)
{
    int gid = blockIdx.x * 256 + threadIdx.x;  // 0..32767
    int u = gid & (U - 1);
    int b = gid >> 9;
    float z[4];
#pragma unroll
    for (int g = 0; g < 4; ++g) {
        float s = b_lstm[g * U + u];
#pragma unroll
        for (int c = 0; c < 8; ++c)
            s += zpart[(size_t)(c * B + b) * ZW + g * U + u];
        z[g] = s;
    }
    float co = cin[b * U + u];
    float ig = sigf(z[0]);
    float fg = sigf(z[1]);
    float gg = tanhf(z[2]);
    float og = sigf(z[3]);
    float cn = fg * co + ig * gg;
    float hn = og * tanhf(cn);
    cout[b * U + u] = cn;
    hout[b * U + u] = hn;
}

// logits + fused argmax. grid 512 blocks (12 idle), block 256.
// Block: 256 v x 16 b. Thread: 4 consecutive v (lane*4) x 4 consecutive b (tb*4).
// Per el: 1 global dwordx4 of Wd + 1 broadcast ds_read_b128 of h -> 16 FMA.
// XCD swizzle: the 4 b-tiles of each v-stripe land on the same XCD (Wd L2/L3 reuse).
__global__ __launch_bounds__(256) void logits_kernel(
    const float* __restrict__ h, const float* __restrict__ Wd,
    const float* __restrict__ bd, float* __restrict__ out,
    unsigned long long* __restrict__ slot, int t)
{
    __shared__ float hT[512][20];   // 40 KB; rows 80B -> 16B-aligned float4, broadcast reads conflict-free
    const int bid = blockIdx.x;
    const int x = bid & 7;            // XCD (round-robin heuristic)
    const int j5 = bid >> 3;          // 0..63
    const int btile = j5 & 3;
    const int vtile = x * 16 + (j5 >> 2);   // 0..127
    if (vtile >= 125) return;

    const int tid = threadIdx.x;
    const int lane = tid & 63;
    const int tb = tid >> 6;          // wave-uniform
    const int v0 = vtile * 256 + lane * 4;
    const int b0 = btile * 16;

    // stage h[b0..b0+15][0..511] transposed into LDS
#pragma unroll
    for (int i = 0; i < 32; ++i) {
        int li = tid + 256 * i;       // 0..8191
        int el = li & 511;
        int b  = li >> 9;
        hT[el][b] = h[(b0 + b) * U + el];
    }
    __syncthreads();

    float4 bias = *(const float4*)&bd[v0];
    float acc[4][4];
#pragma unroll
    for (int j = 0; j < 4; ++j) {
        acc[j][0] = bias.x; acc[j][1] = bias.y; acc[j][2] = bias.z; acc[j][3] = bias.w;
    }

#pragma unroll 8
    for (int el = 0; el < 512; ++el) {
        float4 w = *(const float4*)&Wd[(size_t)el * V + v0];
        float4 hh = *(const float4*)&hT[el][tb * 4];   // broadcast
        acc[0][0] = fmaf(hh.x, w.x, acc[0][0]); acc[0][1] = fmaf(hh.x, w.y, acc[0][1]);
        acc[0][2] = fmaf(hh.x, w.z, acc[0][2]); acc[0][3] = fmaf(hh.x, w.w, acc[0][3]);
        acc[1][0] = fmaf(hh.y, w.x, acc[1][0]); acc[1][1] = fmaf(hh.y, w.y, acc[1][1]);
        acc[1][2] = fmaf(hh.y, w.z, acc[1][2]); acc[1][3] = fmaf(hh.y, w.w, acc[1][3]);
        acc[2][0] = fmaf(hh.z, w.x, acc[2][0]); acc[2][1] = fmaf(hh.z, w.y, acc[2][1]);
        acc[2][2] = fmaf(hh.z, w.z, acc[2][2]); acc[2][3] = fmaf(hh.z, w.w, acc[2][3]);
        acc[3][0] = fmaf(hh.w, w.x, acc[3][0]); acc[3][1] = fmaf(hh.w, w.y, acc[3][1]);
        acc[3][2] = fmaf(hh.w, w.z, acc[3][2]); acc[3][3] = fmaf(hh.w, w.w, acc[3][3]);
    }

    // write logits: out[b][t][v0..v0+3]
#pragma unroll
    for (int j = 0; j < 4; ++j) {
        int b = b0 + tb * 4 + j;
        float4 r = make_float4(acc[j][0], acc[j][1], acc[j][2], acc[j][3]);
        *(float4*)&out[(size_t)b * (T_STEPS * V) + (size_t)t * V + v0] = r;
    }

    // fused argmax: monotone-float key, tie-break to smallest v (np.argmax = first max)
#pragma unroll
    for (int j = 0; j < 4; ++j) {
        unsigned long long key = 0ull;
#pragma unroll
        for (int k = 0; k < 4; ++k) {
            unsigned ub = __float_as_uint(acc[j][k]);
            unsigned key32 = (ub & 0x80000000u) ? ~ub : (ub | 0x80000000u);
            unsigned long long kk =
                ((unsigned long long)key32 << 32) | (unsigned long long)(0xFFFFFFFFu - (unsigned)(v0 + k));
            if (kk > key) key = kk;
        }
#pragma unroll
        for (int d = 32; d > 0; d >>= 1) {
            unsigned long long o = __shfl_down(key, (unsigned)d, 64);
            if (o > key) key = o;
        }
        if (lane == 0) atomicMax(slot + (b0 + tb * 4 + j), key);
    }
}

extern "C" void kernel_launch(void* const* d_in, const int* in_sizes, int n_in,
                              void* d_out, int out_size, void* d_ws, size_t ws_size,
                              hipStream_t stream)
{
    const float* h0     = (const float*)d_in[0];
    const float* c0     = (const float*)d_in[1];
    const float* emb    = (const float*)d_in[2];
    const float* Wx     = (const float*)d_in[3];
    const float* Wh     = (const float*)d_in[4];
    const float* b_lstm = (const float*)d_in[5];
    const float* Wd     = (const float*)d_in[6];
    const float* bd     = (const float*)d_in[7];
    float* out = (float*)d_out;

    char* ws = (char*)d_ws;
    unsigned long long* slots = (unsigned long long*)ws;          // [T][B]
    float* zpart = (float*)(ws + WS_ZPART_OFF);                   // [8][B][ZW]
    float* hbuf  = (float*)(ws + WS_ZPART_OFF + WS_ZPART_BYTES);  // [B][U]
    float* cbuf  = hbuf + B * U;                                  // [B][U]

    reset_slots_kernel<<<dim3(5), dim3(256), 0, stream>>>(slots);

    for (int t = 0; t < T_STEPS; ++t) {
        const float* hprev = (t == 0) ? h0 : hbuf;
        const float* cprev = (t == 0) ? c0 : cbuf;
        const unsigned long long* sp = (t == 0) ? slots : (slots + (size_t)(t - 1) * B);

        lstmA_kernel<<<dim3(8, 4, 8), dim3(256), 0, stream>>>(
            emb, Wx, Wh, hprev, sp, zpart, (t == 0) ? 1 : 0);
        lstmB_kernel<<<dim3(128), dim3(256), 0, stream>>>(
            zpart, b_lstm, cprev, hbuf, cbuf);
        logits_kernel<<<dim3(512), dim3(256), 0, stream>>>(
            hbuf, Wd, bd, out, slots + (size_t)t * B, t);
    }
}

// Round 3
// 1310.119 us; speedup vs baseline: 2.7060x; 1.3154x over previous
//
#include <hip/hip_runtime.h>
#include <stdint.h>

#define B 64
#define U 512
#define EDIM 512
#define V 32000
#define T_STEPS 20
#define ZW 2048   // 4*U

typedef __attribute__((ext_vector_type(8))) short bf16x8;
typedef __attribute__((ext_vector_type(4))) float f32x4;

// ---------------- ws layout ----------------
// slots : u64 [T][B]            @ 0         (pad to 16384)
// zpart : f32 [8][B][ZW]        @ 16384     (4 MiB)
// hbuf  : f32 [B][U]
// cbuf  : f32 [B][U]
// hhi   : u16 [B][U]   (bf16 hi plane of h)
// hlo   : u16 [B][U]   (bf16 lo plane)
// wthi  : u16 [V][U]   (bf16 hi plane of Wd, TRANSPOSED [n][k])
// wtlo  : u16 [V][U]
#define WS_ZPART_OFF 16384
#define WS_ZPART_BYTES (8 * B * ZW * 4)

__device__ __forceinline__ float sigf(float x) { return 1.0f / (1.0f + expf(-x)); }

__device__ __forceinline__ unsigned short f32_to_bf16(float x) {
    unsigned u = __float_as_uint(x);
    unsigned r = (u + 0x7fffu + ((u >> 16) & 1u)) >> 16;   // RNE (finite data)
    return (unsigned short)r;
}

__global__ __launch_bounds__(256) void reset_slots_kernel(unsigned long long* __restrict__ slots) {
    int gid = blockIdx.x * 256 + threadIdx.x;
    if (gid < T_STEPS * B) slots[gid] = 0ull;
}

// One-time per call: split Wd[k][n] fp32 into bf16 hi/lo planes, TRANSPOSED to [n][k].
// grid (V/64, K/64) = (500, 8), block 256. 64x64 tile via LDS.
__global__ __launch_bounds__(256) void wd_split_kernel(
    const float* __restrict__ Wd, unsigned short* __restrict__ wthi,
    unsigned short* __restrict__ wtlo)
{
    __shared__ float tile[64][65];
    const int n0 = blockIdx.x * 64;
    const int k0 = blockIdx.y * 64;
    const int tid = threadIdx.x;
#pragma unroll
    for (int i = 0; i < 16; ++i) {
        int li = tid + 256 * i;          // 0..4095
        int k = li >> 6, n = li & 63;    // coalesced read along n
        tile[n][k] = Wd[(size_t)(k0 + k) * V + (n0 + n)];
    }
    __syncthreads();
#pragma unroll
    for (int i = 0; i < 16; ++i) {
        int li = tid + 256 * i;
        int n = li >> 6, k = li & 63;    // coalesced write along k
        float x = tile[n][k];
        unsigned short hb = f32_to_bf16(x);
        float hf = __uint_as_float(((unsigned)hb) << 16);
        unsigned short lb = f32_to_bf16(x - hf);
        size_t o = (size_t)(n0 + n) * U + (k0 + k);
        wthi[o] = hb;
        wtlo[o] = lb;
    }
}

// z-partials (unchanged from round 2). grid (8 ugtiles, 4 btiles, 8 kchunks), block 256.
__global__ __launch_bounds__(256) void lstmA_kernel(
    const float* __restrict__ emb, const float* __restrict__ Wx,
    const float* __restrict__ Wh, const float* __restrict__ hprev,
    const unsigned long long* __restrict__ slot_prev,
    float* __restrict__ zpart, int is_first)
{
    __shared__ float xh[128][20];
    __shared__ int sidx[16];

    const int tid = threadIdx.x;
    const int ugtile = blockIdx.x;
    const int btile = blockIdx.y;
    const int chunk = blockIdx.z;
    const int e0 = chunk * 128;
    const int b0 = btile * 16;

    if (tid < 16) {
        int idx = 1;  // GO token
        if (!is_first) {
            unsigned long long k = slot_prev[b0 + tid];
            idx = (int)(0xFFFFFFFFu - (unsigned)(k & 0xFFFFFFFFull));
        }
        sidx[tid] = idx;
    }
    __syncthreads();

#pragma unroll
    for (int i = 0; i < 8; ++i) {
        int li = tid + 256 * i;
        int el = li & 127;
        int b  = li >> 7;
        float v;
        if (chunk < 4) v = emb[(size_t)sidx[b] * EDIM + (e0 + el)];
        else           v = hprev[(b0 + b) * U + (e0 - EDIM + el)];
        xh[el][b] = v;
    }
    __syncthreads();

    const int lane = tid & 63;
    const int tb = tid >> 6;
    const int ug0 = ugtile * 256 + lane * 4;

    const float* wbase = (chunk < 4) ? (Wx + (size_t)e0 * ZW)
                                     : (Wh + (size_t)(e0 - EDIM) * ZW);
    float acc[4][4];
#pragma unroll
    for (int j = 0; j < 4; ++j)
#pragma unroll
        for (int k = 0; k < 4; ++k) acc[j][k] = 0.0f;

#pragma unroll 8
    for (int el = 0; el < 128; ++el) {
        float4 w = *(const float4*)&wbase[(size_t)el * ZW + ug0];
        float4 hh = *(const float4*)&xh[el][tb * 4];
        acc[0][0] = fmaf(hh.x, w.x, acc[0][0]); acc[0][1] = fmaf(hh.x, w.y, acc[0][1]);
        acc[0][2] = fmaf(hh.x, w.z, acc[0][2]); acc[0][3] = fmaf(hh.x, w.w, acc[0][3]);
        acc[1][0] = fmaf(hh.y, w.x, acc[1][0]); acc[1][1] = fmaf(hh.y, w.y, acc[1][1]);
        acc[1][2] = fmaf(hh.y, w.z, acc[1][2]); acc[1][3] = fmaf(hh.y, w.w, acc[1][3]);
        acc[2][0] = fmaf(hh.z, w.x, acc[2][0]); acc[2][1] = fmaf(hh.z, w.y, acc[2][1]);
        acc[2][2] = fmaf(hh.z, w.z, acc[2][2]); acc[2][3] = fmaf(hh.z, w.w, acc[2][3]);
        acc[3][0] = fmaf(hh.w, w.x, acc[3][0]); acc[3][1] = fmaf(hh.w, w.y, acc[3][1]);
        acc[3][2] = fmaf(hh.w, w.z, acc[3][2]); acc[3][3] = fmaf(hh.w, w.w, acc[3][3]);
    }

#pragma unroll
    for (int j = 0; j < 4; ++j) {
        int b = b0 + tb * 4 + j;
        float4 r = make_float4(acc[j][0], acc[j][1], acc[j][2], acc[j][3]);
        *(float4*)&zpart[(size_t)chunk * (B * ZW) + (size_t)b * ZW + ug0] = r;
    }
}

// gates + state update; also emits bf16 hi/lo planes of h for the MFMA logits path.
__global__ __launch_bounds__(256) void lstmB_kernel(
    const float* __restrict__ zpart, const float* __restrict__ b_lstm,
    const float* __restrict__ cin, float* __restrict__ hout, float* __restrict__ cout,
    unsigned short* __restrict__ hhi, unsigned short* __restrict__ hlo)
{
    int gid = blockIdx.x * 256 + threadIdx.x;
    int u = gid & (U - 1);
    int b = gid >> 9;
    float z[4];
#pragma unroll
    for (int g = 0; g < 4; ++g) {
        float s = b_lstm[g * U + u];
#pragma unroll
        for (int c = 0; c < 8; ++c)
            s += zpart[(size_t)(c * B + b) * ZW + g * U + u];
        z[g] = s;
    }
    float co = cin[b * U + u];
    float ig = sigf(z[0]);
    float fg = sigf(z[1]);
    float gg = tanhf(z[2]);
    float og = sigf(z[3]);
    float cn = fg * co + ig * gg;
    float hn = og * tanhf(cn);
    cout[b * U + u] = cn;
    hout[b * U + u] = hn;
    if (hhi) {
        unsigned short hb = f32_to_bf16(hn);
        float hf = __uint_as_float(((unsigned)hb) << 16);
        hhi[b * U + u] = hb;
        hlo[b * U + u] = f32_to_bf16(hn - hf);
    }
}

// MFMA logits + fused argmax. grid 250 blocks (1/CU), block 256 (4 waves).
// Block: 128 v x 64 b x K=512, split-bf16: D = h_hi@W_hi + h_lo@W_hi + h_hi@W_lo.
// Wave w: n-tiles {w*32, w*32+16}; all 4 m-tiles. NO LDS in K-loop: A-frags from
// h hi/lo planes ([m][k], 16B/lane contiguous), B-frags from transposed Wd planes
// ([n][k], 16B/lane contiguous). Wd read exactly once per step (65.5 MB, L3-resident).
__global__ __launch_bounds__(256) void logits_mfma_kernel(
    const unsigned short* __restrict__ hhi, const unsigned short* __restrict__ hlo,
    const unsigned short* __restrict__ wthi, const unsigned short* __restrict__ wtlo,
    const float* __restrict__ bd, float* __restrict__ out,
    unsigned long long* __restrict__ slot, int t)
{
    __shared__ unsigned long long smax[B];
    const int tid = threadIdx.x;
    const int lane = tid & 63;
    const int wv = tid >> 6;           // 0..3
    const int l15 = lane & 15;
    const int q = lane >> 4;           // quad 0..3
    const int nbase = blockIdx.x * 128 + wv * 32;

    if (tid < B) smax[tid] = 0ull;

    f32x4 acc[2][4];                   // [nt][mt]
    {
        float b0v = bd[nbase + l15];
        float b1v = bd[nbase + 16 + l15];
#pragma unroll
        for (int mt = 0; mt < 4; ++mt) {
            acc[0][mt] = (f32x4){b0v, b0v, b0v, b0v};
            acc[1][mt] = (f32x4){b1v, b1v, b1v, b1v};
        }
    }

    const unsigned short* pa_h = hhi + l15 * U + q * 8;
    const unsigned short* pa_l = hlo + l15 * U + q * 8;
    const unsigned short* pb_h = wthi + (size_t)(nbase + l15) * U + q * 8;
    const unsigned short* pb_l = wtlo + (size_t)(nbase + l15) * U + q * 8;

#pragma unroll 2
    for (int ks = 0; ks < 16; ++ks) {
        const int ko = ks * 32;
        bf16x8 bh0 = *(const bf16x8*)(pb_h + ko);
        bf16x8 bh1 = *(const bf16x8*)(pb_h + 16 * U + ko);
        bf16x8 bl0 = *(const bf16x8*)(pb_l + ko);
        bf16x8 bl1 = *(const bf16x8*)(pb_l + 16 * U + ko);
        bf16x8 ah[4], al[4];
#pragma unroll
        for (int mt = 0; mt < 4; ++mt) {
            ah[mt] = *(const bf16x8*)(pa_h + mt * 16 * U + ko);
            al[mt] = *(const bf16x8*)(pa_l + mt * 16 * U + ko);
        }
        // independent acc chains: touch each acc 3x with distance 8
#pragma unroll
        for (int mt = 0; mt < 4; ++mt)
            acc[0][mt] = __builtin_amdgcn_mfma_f32_16x16x32_bf16(ah[mt], bh0, acc[0][mt], 0, 0, 0);
#pragma unroll
        for (int mt = 0; mt < 4; ++mt)
            acc[1][mt] = __builtin_amdgcn_mfma_f32_16x16x32_bf16(ah[mt], bh1, acc[1][mt], 0, 0, 0);
#pragma unroll
        for (int mt = 0; mt < 4; ++mt)
            acc[0][mt] = __builtin_amdgcn_mfma_f32_16x16x32_bf16(al[mt], bh0, acc[0][mt], 0, 0, 0);
#pragma unroll
        for (int mt = 0; mt < 4; ++mt)
            acc[1][mt] = __builtin_amdgcn_mfma_f32_16x16x32_bf16(al[mt], bh1, acc[1][mt], 0, 0, 0);
#pragma unroll
        for (int mt = 0; mt < 4; ++mt)
            acc[0][mt] = __builtin_amdgcn_mfma_f32_16x16x32_bf16(ah[mt], bl0, acc[0][mt], 0, 0, 0);
#pragma unroll
        for (int mt = 0; mt < 4; ++mt)
            acc[1][mt] = __builtin_amdgcn_mfma_f32_16x16x32_bf16(ah[mt], bl1, acc[1][mt], 0, 0, 0);
    }
    __syncthreads();   // smax init visible

    // write logits: D[m][n] -> m = mt*16 + q*4 + r (batch), n = nbase + nt*16 + l15 (vocab)
#pragma unroll
    for (int nt = 0; nt < 2; ++nt) {
        int v = nbase + nt * 16 + l15;
#pragma unroll
        for (int mt = 0; mt < 4; ++mt)
#pragma unroll
            for (int r = 0; r < 4; ++r) {
                int b = mt * 16 + q * 4 + r;
                out[(size_t)b * (T_STEPS * V) + (size_t)t * V + v] = acc[nt][mt][r];
            }
    }

    // fused argmax: monotone key, tie-break to smallest v (np.argmax = first max)
#pragma unroll
    for (int mt = 0; mt < 4; ++mt)
#pragma unroll
        for (int r = 0; r < 4; ++r) {
            int b = mt * 16 + q * 4 + r;
            unsigned long long key = 0ull;
#pragma unroll
            for (int nt = 0; nt < 2; ++nt) {
                float val = acc[nt][mt][r];
                int v = nbase + nt * 16 + l15;
                unsigned ub = __float_as_uint(val);
                unsigned k32 = (ub & 0x80000000u) ? ~ub : (ub | 0x80000000u);
                unsigned long long kk =
                    ((unsigned long long)k32 << 32) | (unsigned long long)(0xFFFFFFFFu - (unsigned)v);
                if (kk > key) key = kk;
            }
#pragma unroll
            for (int m = 8; m >= 1; m >>= 1) {
                unsigned long long o = __shfl_xor(key, m, 64);   // stays within 16-lane group
                if (o > key) key = o;
            }
            if (l15 == 0) atomicMax(&smax[b], key);
        }
    __syncthreads();
    if (tid < B) atomicMax(slot + tid, smax[tid]);
}

// Fallback fp32 logits (round-2 kernel) if ws is too small for the Wd planes.
__global__ __launch_bounds__(256) void logits_kernel(
    const float* __restrict__ h, const float* __restrict__ Wd,
    const float* __restrict__ bd, float* __restrict__ out,
    unsigned long long* __restrict__ slot, int t)
{
    __shared__ float hT[512][20];
    const int bid = blockIdx.x;
    const int x = bid & 7;
    const int j5 = bid >> 3;
    const int btile = j5 & 3;
    const int vtile = x * 16 + (j5 >> 2);
    if (vtile >= 125) return;

    const int tid = threadIdx.x;
    const int lane = tid & 63;
    const int tb = tid >> 6;
    const int v0 = vtile * 256 + lane * 4;
    const int b0 = btile * 16;

#pragma unroll
    for (int i = 0; i < 32; ++i) {
        int li = tid + 256 * i;
        int el = li & 511;
        int b  = li >> 9;
        hT[el][b] = h[(b0 + b) * U + el];
    }
    __syncthreads();

    float4 bias = *(const float4*)&bd[v0];
    float acc[4][4];
#pragma unroll
    for (int j = 0; j < 4; ++j) {
        acc[j][0] = bias.x; acc[j][1] = bias.y; acc[j][2] = bias.z; acc[j][3] = bias.w;
    }

#pragma unroll 8
    for (int el = 0; el < 512; ++el) {
        float4 w = *(const float4*)&Wd[(size_t)el * V + v0];
        float4 hh = *(const float4*)&hT[el][tb * 4];
        acc[0][0] = fmaf(hh.x, w.x, acc[0][0]); acc[0][1] = fmaf(hh.x, w.y, acc[0][1]);
        acc[0][2] = fmaf(hh.x, w.z, acc[0][2]); acc[0][3] = fmaf(hh.x, w.w, acc[0][3]);
        acc[1][0] = fmaf(hh.y, w.x, acc[1][0]); acc[1][1] = fmaf(hh.y, w.y, acc[1][1]);
        acc[1][2] = fmaf(hh.y, w.z, acc[1][2]); acc[1][3] = fmaf(hh.y, w.w, acc[1][3]);
        acc[2][0] = fmaf(hh.z, w.x, acc[2][0]); acc[2][1] = fmaf(hh.z, w.y, acc[2][1]);
        acc[2][2] = fmaf(hh.z, w.z, acc[2][2]); acc[2][3] = fmaf(hh.z, w.w, acc[2][3]);
        acc[3][0] = fmaf(hh.w, w.x, acc[3][0]); acc[3][1] = fmaf(hh.w, w.y, acc[3][1]);
        acc[3][2] = fmaf(hh.w, w.z, acc[3][2]); acc[3][3] = fmaf(hh.w, w.w, acc[3][3]);
    }

#pragma unroll
    for (int j = 0; j < 4; ++j) {
        int b = b0 + tb * 4 + j;
        float4 r = make_float4(acc[j][0], acc[j][1], acc[j][2], acc[j][3]);
        *(float4*)&out[(size_t)b * (T_STEPS * V) + (size_t)t * V + v0] = r;
    }

#pragma unroll
    for (int j = 0; j < 4; ++j) {
        unsigned long long key = 0ull;
#pragma unroll
        for (int k = 0; k < 4; ++k) {
            unsigned ub = __float_as_uint(acc[j][k]);
            unsigned key32 = (ub & 0x80000000u) ? ~ub : (ub | 0x80000000u);
            unsigned long long kk =
                ((unsigned long long)key32 << 32) | (unsigned long long)(0xFFFFFFFFu - (unsigned)(v0 + k));
            if (kk > key) key = kk;
        }
#pragma unroll
        for (int d = 32; d > 0; d >>= 1) {
            unsigned long long o = __shfl_down(key, (unsigned)d, 64);
            if (o > key) key = o;
        }
        if (lane == 0) atomicMax(slot + (b0 + tb * 4 + j), key);
    }
}

extern "C" void kernel_launch(void* const* d_in, const int* in_sizes, int n_in,
                              void* d_out, int out_size, void* d_ws, size_t ws_size,
                              hipStream_t stream)
{
    const float* h0     = (const float*)d_in[0];
    const float* c0     = (const float*)d_in[1];
    const float* emb    = (const float*)d_in[2];
    const float* Wx     = (const float*)d_in[3];
    const float* Wh     = (const float*)d_in[4];
    const float* b_lstm = (const float*)d_in[5];
    const float* Wd     = (const float*)d_in[6];
    const float* bd     = (const float*)d_in[7];
    float* out = (float*)d_out;

    char* ws = (char*)d_ws;
    unsigned long long* slots = (unsigned long long*)ws;
    float* zpart = (float*)(ws + WS_ZPART_OFF);
    float* hbuf  = (float*)(ws + WS_ZPART_OFF + WS_ZPART_BYTES);
    float* cbuf  = hbuf + B * U;
    unsigned short* hhi = (unsigned short*)(cbuf + B * U);
    unsigned short* hlo = hhi + B * U;
    unsigned short* wthi = hlo + B * U;
    unsigned short* wtlo = wthi + (size_t)V * U;
    size_t need_full = (size_t)((char*)(wtlo + (size_t)V * U) - ws);
    const bool use_mfma = (ws_size >= need_full);

    reset_slots_kernel<<<dim3(5), dim3(256), 0, stream>>>(slots);
    if (use_mfma)
        wd_split_kernel<<<dim3(V / 64, U / 64), dim3(256), 0, stream>>>(Wd, wthi, wtlo);

    for (int t = 0; t < T_STEPS; ++t) {
        const float* hprev = (t == 0) ? h0 : hbuf;
        const float* cprev = (t == 0) ? c0 : cbuf;
        const unsigned long long* sp = (t == 0) ? slots : (slots + (size_t)(t - 1) * B);

        lstmA_kernel<<<dim3(8, 4, 8), dim3(256), 0, stream>>>(
            emb, Wx, Wh, hprev, sp, zpart, (t == 0) ? 1 : 0);
        lstmB_kernel<<<dim3(128), dim3(256), 0, stream>>>(
            zpart, b_lstm, cprev, hbuf, cbuf,
            use_mfma ? hhi : (unsigned short*)nullptr,
            use_mfma ? hlo : (unsigned short*)nullptr);
        if (use_mfma)
            logits_mfma_kernel<<<dim3(250), dim3(256), 0, stream>>>(
                hhi, hlo, wthi, wtlo, bd, out, slots + (size_t)t * B, t);
        else
            logits_kernel<<<dim3(512), dim3(256), 0, stream>>>(
                hbuf, Wd, bd, out, slots + (size_t)t * B, t);
    }
}